// Round 1
// baseline (2527.961 us; speedup 1.0000x reference)
//
#include <hip/hip_runtime.h>

// Problem constants (from reference)
#define BB 8
#define FF 64
#define NPTS 100000
#define RES 32
#define R3 (RES*RES*RES)
#define EPSV 1e-6f

static constexpr size_t GRID_ELEMS = (size_t)BB * FF * R3;   // 16,777,216
static constexpr size_t NORM_ELEMS = (size_t)BB * 3 * NPTS;  // 2,400,000

// ---------------- Kernel A: per-batch coordinate sums ----------------
#define NB_STAT 64
__global__ void k_sum_coords(const float* __restrict__ coords, float* __restrict__ sums) {
    int b = blockIdx.x / NB_STAT;
    int chunk = blockIdx.x % NB_STAT;
    const float* cb = coords + (size_t)b * 3 * NPTS;
    float sx = 0.f, sy = 0.f, sz = 0.f;
    for (int i = chunk * blockDim.x + threadIdx.x; i < NPTS; i += NB_STAT * blockDim.x) {
        sx += cb[i];
        sy += cb[NPTS + i];
        sz += cb[2 * NPTS + i];
    }
    // wave (64-lane) reduce
    for (int off = 32; off; off >>= 1) {
        sx += __shfl_down(sx, off);
        sy += __shfl_down(sy, off);
        sz += __shfl_down(sz, off);
    }
    __shared__ float lsx[4], lsy[4], lsz[4];
    int lane = threadIdx.x & 63, wid = threadIdx.x >> 6;
    if (lane == 0) { lsx[wid] = sx; lsy[wid] = sy; lsz[wid] = sz; }
    __syncthreads();
    if (threadIdx.x == 0) {
        float tx = 0.f, ty = 0.f, tz = 0.f;
        for (int w = 0; w < 4; ++w) { tx += lsx[w]; ty += lsy[w]; tz += lsz[w]; }
        atomicAdd(&sums[b * 3 + 0], tx);
        atomicAdd(&sums[b * 3 + 1], ty);
        atomicAdd(&sums[b * 3 + 2], tz);
    }
}

// ---------------- Kernel B: per-batch max radius ----------------
__global__ void k_radius(const float* __restrict__ coords, const float* __restrict__ sums,
                         int* __restrict__ rad_bits) {
    int b = blockIdx.x / NB_STAT;
    int chunk = blockIdx.x % NB_STAT;
    const float* cb = coords + (size_t)b * 3 * NPTS;
    float mx = sums[b * 3 + 0] / (float)NPTS;
    float my = sums[b * 3 + 1] / (float)NPTS;
    float mz = sums[b * 3 + 2] / (float)NPTS;
    float mval = 0.f;
    for (int i = chunk * blockDim.x + threadIdx.x; i < NPTS; i += NB_STAT * blockDim.x) {
        float x = cb[i] - mx;
        float y = cb[NPTS + i] - my;
        float z = cb[2 * NPTS + i] - mz;
        float nrm = sqrtf(x * x + y * y + z * z);
        mval = fmaxf(mval, nrm);
    }
    for (int off = 32; off; off >>= 1) mval = fmaxf(mval, __shfl_down(mval, off));
    __shared__ float lm[4];
    int lane = threadIdx.x & 63, wid = threadIdx.x >> 6;
    if (lane == 0) lm[wid] = mval;
    __syncthreads();
    if (threadIdx.x == 0) {
        float t = fmaxf(fmaxf(lm[0], lm[1]), fmaxf(lm[2], lm[3]));
        atomicMax(&rad_bits[b], __float_as_int(t));  // norms >= 0: int order == float order
    }
}

// ---------------- Kernel C: per-point voxelize + norm_coords + counts ----------------
__global__ void k_voxelize(const float* __restrict__ coords, const float* __restrict__ sums,
                           const int* __restrict__ rad_bits, float* __restrict__ norm_out,
                           int* __restrict__ voxidx, float* __restrict__ counts) {
    int tid = blockIdx.x * blockDim.x + threadIdx.x;
    if (tid >= BB * NPTS) return;
    int b = tid / NPTS, n = tid % NPTS;
    const float* cb = coords + (size_t)b * 3 * NPTS;
    float mx = sums[b * 3 + 0] / (float)NPTS;
    float my = sums[b * 3 + 1] / (float)NPTS;
    float mz = sums[b * 3 + 2] / (float)NPTS;
    float r = __int_as_float(rad_bits[b]);
    float s = 1.0f / (2.0f * r + EPSV);
    float x = (cb[n] - mx) * s + 0.5f;
    float y = (cb[NPTS + n] - my) * s + 0.5f;
    float z = (cb[2 * NPTS + n] - mz) * s + 0.5f;
    float nx = fminf(fmaxf(x * (float)RES, 0.0f), (float)(RES - 1));
    float ny = fminf(fmaxf(y * (float)RES, 0.0f), (float)(RES - 1));
    float nz = fminf(fmaxf(z * (float)RES, 0.0f), (float)(RES - 1));
    float* nb_ = norm_out + (size_t)b * 3 * NPTS;
    nb_[n] = nx;
    nb_[NPTS + n] = ny;
    nb_[2 * NPTS + n] = nz;
    int vx = (int)rintf(nx), vy = (int)rintf(ny), vz = (int)rintf(nz);
    int idx = (vx * RES + vy) * RES + vz;
    voxidx[tid] = idx;
    atomicAdd(&counts[b * R3 + idx], 1.0f);
}

// ---------------- Kernel D: scatter features into grid sums ----------------
__global__ void k_scatter(const float* __restrict__ features, const int* __restrict__ voxidx,
                          float* __restrict__ grid) {
    size_t tid = (size_t)blockIdx.x * blockDim.x + threadIdx.x;
    if (tid >= (size_t)BB * FF * NPTS) return;
    int n = (int)(tid % NPTS);
    int bf = (int)(tid / NPTS);  // b*FF + f
    int b = bf >> 6;             // FF == 64
    int idx = voxidx[b * NPTS + n];
    float v = features[tid];  // features flat index [b][f][n] == bf*NPTS + n == tid
    atomicAdd(&grid[(size_t)bf * R3 + idx], v);
}

// ---------------- Kernel E: normalize (sum -> avg) ----------------
__global__ void k_normalize(float* __restrict__ grid, const float* __restrict__ counts) {
    size_t tid = (size_t)blockIdx.x * blockDim.x + threadIdx.x;
    if (tid >= GRID_ELEMS) return;
    int v = (int)(tid % R3);
    int bf = (int)(tid / R3);
    int b = bf >> 6;
    float c = counts[b * R3 + v];
    grid[tid] = grid[tid] / fmaxf(c, 1.0f);
}

extern "C" void kernel_launch(void* const* d_in, const int* in_sizes, int n_in,
                              void* d_out, int out_size, void* d_ws, size_t ws_size,
                              hipStream_t stream) {
    const float* features = (const float*)d_in[0];
    const float* coords = (const float*)d_in[1];
    float* out = (float*)d_out;
    float* grid = out;                      // [B,F,R,R,R]
    float* norm_out = out + GRID_ELEMS;     // [B,3,N]

    char* ws = (char*)d_ws;
    float* sums = (float*)ws;                                 // 24 floats
    int* rad_bits = (int*)(ws + 128);                         // 8 ints
    float* counts = (float*)(ws + 256);                       // B*R3 floats = 1 MB
    int* voxidx = (int*)(ws + 256 + (size_t)BB * R3 * 4);     // B*N ints = 3.2 MB

    // zero stats + counts, and the grid accumulation region of d_out
    hipMemsetAsync(d_ws, 0, 256 + (size_t)BB * R3 * 4, stream);
    hipMemsetAsync(grid, 0, GRID_ELEMS * sizeof(float), stream);

    k_sum_coords<<<BB * NB_STAT, 256, 0, stream>>>(coords, sums);
    k_radius<<<BB * NB_STAT, 256, 0, stream>>>(coords, sums, rad_bits);

    int pts_blocks = (BB * NPTS + 255) / 256;
    k_voxelize<<<pts_blocks, 256, 0, stream>>>(coords, sums, rad_bits, norm_out, voxidx, counts);

    size_t scatter_threads = (size_t)BB * FF * NPTS;
    int scatter_blocks = (int)((scatter_threads + 255) / 256);
    k_scatter<<<scatter_blocks, 256, 0, stream>>>(features, voxidx, grid);

    int norm_blocks = (int)((GRID_ELEMS + 255) / 256);
    k_normalize<<<norm_blocks, 256, 0, stream>>>(grid, counts);
}

// Round 2
// 397.623 us; speedup vs baseline: 6.3577x; 6.3577x over previous
//
#include <hip/hip_runtime.h>

#define BB 8
#define FF 64
#define NPTS 100000
#define RES 32
#define R3 (RES*RES*RES)
#define EPSV 1e-6f
#define SEGS (BB*R3)            // 262144 voxel segments
#define NPTS_TOT (BB*NPTS)      // 800000 points

static constexpr size_t GRID_ELEMS = (size_t)BB * FF * R3;   // 16,777,216

// ---------------- Kernel A: per-batch coordinate sums ----------------
#define NB_STAT 64
__global__ void k_sum_coords(const float* __restrict__ coords, float* __restrict__ sums) {
    int b = blockIdx.x / NB_STAT;
    int chunk = blockIdx.x % NB_STAT;
    const float* cb = coords + (size_t)b * 3 * NPTS;
    float sx = 0.f, sy = 0.f, sz = 0.f;
    for (int i = chunk * blockDim.x + threadIdx.x; i < NPTS; i += NB_STAT * blockDim.x) {
        sx += cb[i];
        sy += cb[NPTS + i];
        sz += cb[2 * NPTS + i];
    }
    for (int off = 32; off; off >>= 1) {
        sx += __shfl_down(sx, off);
        sy += __shfl_down(sy, off);
        sz += __shfl_down(sz, off);
    }
    __shared__ float lsx[4], lsy[4], lsz[4];
    int lane = threadIdx.x & 63, wid = threadIdx.x >> 6;
    if (lane == 0) { lsx[wid] = sx; lsy[wid] = sy; lsz[wid] = sz; }
    __syncthreads();
    if (threadIdx.x == 0) {
        float tx = 0.f, ty = 0.f, tz = 0.f;
        for (int w = 0; w < 4; ++w) { tx += lsx[w]; ty += lsy[w]; tz += lsz[w]; }
        atomicAdd(&sums[b * 3 + 0], tx);
        atomicAdd(&sums[b * 3 + 1], ty);
        atomicAdd(&sums[b * 3 + 2], tz);
    }
}

// ---------------- Kernel B: per-batch max radius ----------------
__global__ void k_radius(const float* __restrict__ coords, const float* __restrict__ sums,
                         int* __restrict__ rad_bits) {
    int b = blockIdx.x / NB_STAT;
    int chunk = blockIdx.x % NB_STAT;
    const float* cb = coords + (size_t)b * 3 * NPTS;
    float mx = sums[b * 3 + 0] / (float)NPTS;
    float my = sums[b * 3 + 1] / (float)NPTS;
    float mz = sums[b * 3 + 2] / (float)NPTS;
    float mval = 0.f;
    for (int i = chunk * blockDim.x + threadIdx.x; i < NPTS; i += NB_STAT * blockDim.x) {
        float x = cb[i] - mx;
        float y = cb[NPTS + i] - my;
        float z = cb[2 * NPTS + i] - mz;
        float nrm = sqrtf(x * x + y * y + z * z);
        mval = fmaxf(mval, nrm);
    }
    for (int off = 32; off; off >>= 1) mval = fmaxf(mval, __shfl_down(mval, off));
    __shared__ float lm[4];
    int lane = threadIdx.x & 63, wid = threadIdx.x >> 6;
    if (lane == 0) lm[wid] = mval;
    __syncthreads();
    if (threadIdx.x == 0) {
        float t = fmaxf(fmaxf(lm[0], lm[1]), fmaxf(lm[2], lm[3]));
        atomicMax(&rad_bits[b], __float_as_int(t));  // norms >= 0: int order == float order
    }
}

// ---------------- Kernel C: per-point voxelize + norm_coords + counts ----------------
__global__ void k_voxelize(const float* __restrict__ coords, const float* __restrict__ sums,
                           const int* __restrict__ rad_bits, float* __restrict__ norm_out,
                           int* __restrict__ voxidx, int* __restrict__ counts) {
    int tid = blockIdx.x * blockDim.x + threadIdx.x;
    if (tid >= NPTS_TOT) return;
    int b = tid / NPTS, n = tid % NPTS;
    const float* cb = coords + (size_t)b * 3 * NPTS;
    float mx = sums[b * 3 + 0] / (float)NPTS;
    float my = sums[b * 3 + 1] / (float)NPTS;
    float mz = sums[b * 3 + 2] / (float)NPTS;
    float r = __int_as_float(rad_bits[b]);
    float d = 2.0f * r + EPSV;
    float x = (cb[n] - mx) / d + 0.5f;
    float y = (cb[NPTS + n] - my) / d + 0.5f;
    float z = (cb[2 * NPTS + n] - mz) / d + 0.5f;
    float nx = fminf(fmaxf(x * (float)RES, 0.0f), (float)(RES - 1));
    float ny = fminf(fmaxf(y * (float)RES, 0.0f), (float)(RES - 1));
    float nz = fminf(fmaxf(z * (float)RES, 0.0f), (float)(RES - 1));
    float* nb_ = norm_out + (size_t)b * 3 * NPTS;
    nb_[n] = nx;
    nb_[NPTS + n] = ny;
    nb_[2 * NPTS + n] = nz;
    int vx = (int)rintf(nx), vy = (int)rintf(ny), vz = (int)rintf(nz);
    int idx = (vx * RES + vy) * RES + vz;
    voxidx[tid] = idx;
    atomicAdd(&counts[b * R3 + idx], 1);
}

// ---------------- Scan: exclusive prefix sum over SEGS counts ----------------
// scan1: 256 blocks x 1024 elems -> local-exclusive offsets + blocksums
__global__ void k_scan1(const int* __restrict__ counts, int* __restrict__ offsets,
                        int* __restrict__ blocksums) {
    int tid = threadIdx.x, bid = blockIdx.x;
    int base = bid * 1024 + tid * 4;
    int c0 = counts[base], c1 = counts[base + 1], c2 = counts[base + 2], c3 = counts[base + 3];
    int tot = c0 + c1 + c2 + c3;
    int lane = tid & 63, wid = tid >> 6;
    int v = tot;
    for (int off = 1; off < 64; off <<= 1) {
        int u = __shfl_up(v, off);
        if (lane >= off) v += u;
    }
    __shared__ int wtot[4];
    if (lane == 63) wtot[wid] = v;
    __syncthreads();
    int wof = 0;
    for (int w = 0; w < wid; ++w) wof += wtot[w];
    int ex = wof + v - tot;
    offsets[base] = ex;
    offsets[base + 1] = ex + c0;
    offsets[base + 2] = ex + c0 + c1;
    offsets[base + 3] = ex + c0 + c1 + c2;
    if (tid == 0) blocksums[bid] = wtot[0] + wtot[1] + wtot[2] + wtot[3];
}

// scan2: single block, exclusive scan of 256 blocksums -> blockoff
__global__ void k_scan2(const int* __restrict__ blocksums, int* __restrict__ blockoff) {
    int tid = threadIdx.x;
    int c = blocksums[tid];
    int lane = tid & 63, wid = tid >> 6;
    int v = c;
    for (int off = 1; off < 64; off <<= 1) {
        int u = __shfl_up(v, off);
        if (lane >= off) v += u;
    }
    __shared__ int wtot[4];
    if (lane == 63) wtot[wid] = v;
    __syncthreads();
    int wof = 0;
    for (int w = 0; w < wid; ++w) wof += wtot[w];
    blockoff[tid] = wof + v - c;
}

// ---------------- Kernel D: LDS-tiled transpose + scatter into sorted rows ----------------
// featS[row][f], row = offsets(bv) + rank within voxel. 64-point x 64-feature tiles.
__global__ void k_transpose_scatter(const float* __restrict__ features,
                                    const int* __restrict__ voxidx,
                                    const int* __restrict__ offsets,
                                    const int* __restrict__ blockoff,
                                    int* __restrict__ cursors,
                                    float* __restrict__ featS) {
    __shared__ float tileF[64][65];
    __shared__ int dst[64];
    int b = blockIdx.y;
    int n0 = blockIdx.x * 64;
    int tid = threadIdx.x, lane = tid & 63, wid = tid >> 6;

    for (int f = wid; f < 64; f += 4) {
        int n = n0 + lane;
        tileF[f][lane] = (n < NPTS) ? features[((size_t)b * FF + f) * NPTS + n] : 0.f;
    }
    if (tid < 64) {
        int n = n0 + tid;
        if (n < NPTS) {
            int v = voxidx[(size_t)b * NPTS + n];
            int bv = b * R3 + v;
            int r = atomicAdd(&cursors[bv], 1);
            dst[tid] = offsets[bv] + blockoff[bv >> 10] + r;
        } else {
            dst[tid] = -1;
        }
    }
    __syncthreads();
    for (int p = wid; p < 64; p += 4) {
        int d = dst[p];
        if (d >= 0) featS[(size_t)d * 64 + lane] = tileF[lane][p];
    }
}

// ---------------- Kernel E: gather + average + transposed grid write ----------------
__global__ void k_gather(const float* __restrict__ featS, const int* __restrict__ offsets,
                         const int* __restrict__ blockoff, const int* __restrict__ counts,
                         float* __restrict__ grid) {
    __shared__ float tileG[64][65];
    int bv0 = blockIdx.x * 64;
    int tid = threadIdx.x, lane = tid & 63, wid = tid >> 6;
    for (int k = 0; k < 16; ++k) {
        int vl = wid * 16 + k;
        int bv = bv0 + vl;
        int off = offsets[bv] + blockoff[bv >> 10];
        int cnt = counts[bv];
        const float* p = featS + (size_t)off * 64 + lane;
        float a0 = 0.f, a1 = 0.f, a2 = 0.f, a3 = 0.f;
        int i = 0;
        for (; i + 4 <= cnt; i += 4) {
            a0 += p[(size_t)(i + 0) * 64];
            a1 += p[(size_t)(i + 1) * 64];
            a2 += p[(size_t)(i + 2) * 64];
            a3 += p[(size_t)(i + 3) * 64];
        }
        for (; i < cnt; ++i) a0 += p[(size_t)i * 64];
        float acc = (a0 + a1) + (a2 + a3);
        tileG[vl][lane] = (cnt > 0) ? acc / (float)cnt : 0.f;
    }
    __syncthreads();
    int b = bv0 / R3;
    int v0 = bv0 % R3;
    for (int f = wid; f < 64; f += 4) {
        grid[((size_t)b * FF + f) * R3 + v0 + lane] = tileG[lane][f];
    }
}

// ---------------- Fallback path (atomic scatter), used if ws too small ----------------
__global__ void k_scatter(const float* __restrict__ features, const int* __restrict__ voxidx,
                          float* __restrict__ grid) {
    size_t tid = (size_t)blockIdx.x * blockDim.x + threadIdx.x;
    if (tid >= (size_t)BB * FF * NPTS) return;
    int n = (int)(tid % NPTS);
    int bf = (int)(tid / NPTS);
    int b = bf >> 6;
    int idx = voxidx[(size_t)b * NPTS + n];
    atomicAdd(&grid[(size_t)bf * R3 + idx], features[tid]);
}

__global__ void k_normalize(float* __restrict__ grid, const int* __restrict__ counts) {
    size_t tid = (size_t)blockIdx.x * blockDim.x + threadIdx.x;
    if (tid >= GRID_ELEMS) return;
    int v = (int)(tid % R3);
    int bf = (int)(tid / R3);
    int b = bf >> 6;
    float c = (float)counts[b * R3 + v];
    grid[tid] = grid[tid] / fmaxf(c, 1.0f);
}

extern "C" void kernel_launch(void* const* d_in, const int* in_sizes, int n_in,
                              void* d_out, int out_size, void* d_ws, size_t ws_size,
                              hipStream_t stream) {
    const float* features = (const float*)d_in[0];
    const float* coords = (const float*)d_in[1];
    float* out = (float*)d_out;
    float* grid = out;                      // [B,F,R,R,R]
    float* norm_out = out + GRID_ELEMS;     // [B,3,N]

    char* ws = (char*)d_ws;
    // layout
    size_t off_sums   = 0;                            // 24 floats
    size_t off_rad    = 128;                          // 8 ints
    size_t off_counts = 256;                          // SEGS ints (1 MB)
    size_t off_offs   = off_counts + (size_t)SEGS * 4;
    size_t off_curs   = off_offs + (size_t)SEGS * 4;
    size_t off_bsums  = off_curs + (size_t)SEGS * 4;
    size_t off_boff   = off_bsums + 256 * 4;
    size_t off_vox    = off_boff + 256 * 4;           // NPTS_TOT ints (3.2 MB)
    size_t off_featS  = (off_vox + (size_t)NPTS_TOT * 4 + 255) & ~(size_t)255;
    size_t needed     = off_featS + (size_t)NPTS_TOT * FF * 4;  // ~208 MB

    float* sums    = (float*)(ws + off_sums);
    int* rad_bits  = (int*)(ws + off_rad);
    int* counts    = (int*)(ws + off_counts);
    int* offsets   = (int*)(ws + off_offs);
    int* cursors   = (int*)(ws + off_curs);
    int* blocksums = (int*)(ws + off_bsums);
    int* blockoff  = (int*)(ws + off_boff);
    int* voxidx    = (int*)(ws + off_vox);
    float* featS   = (float*)(ws + off_featS);

    bool fast = (ws_size >= needed);

    if (fast) {
        // zero sums/rad/counts/cursors (offsets region included, overwritten anyway)
        hipMemsetAsync(ws, 0, off_bsums, stream);
    } else {
        hipMemsetAsync(ws, 0, off_offs, stream);  // sums/rad/counts only
        hipMemsetAsync(grid, 0, GRID_ELEMS * sizeof(float), stream);
    }

    k_sum_coords<<<BB * NB_STAT, 256, 0, stream>>>(coords, sums);
    k_radius<<<BB * NB_STAT, 256, 0, stream>>>(coords, sums, rad_bits);

    int pts_blocks = (NPTS_TOT + 255) / 256;
    k_voxelize<<<pts_blocks, 256, 0, stream>>>(coords, sums, rad_bits, norm_out, voxidx, counts);

    if (fast) {
        k_scan1<<<256, 256, 0, stream>>>(counts, offsets, blocksums);
        k_scan2<<<1, 256, 0, stream>>>(blocksums, blockoff);
        dim3 tgrid((NPTS + 63) / 64, BB);
        k_transpose_scatter<<<tgrid, 256, 0, stream>>>(features, voxidx, offsets, blockoff,
                                                       cursors, featS);
        k_gather<<<SEGS / 64, 256, 0, stream>>>(featS, offsets, blockoff, counts, grid);
    } else {
        size_t scatter_threads = (size_t)BB * FF * NPTS;
        int scatter_blocks = (int)((scatter_threads + 255) / 256);
        k_scatter<<<scatter_blocks, 256, 0, stream>>>(features, voxidx, grid);
        int norm_blocks = (int)((GRID_ELEMS + 255) / 256);
        k_normalize<<<norm_blocks, 256, 0, stream>>>(grid, counts);
    }
}

// Round 3
// 383.687 us; speedup vs baseline: 6.5886x; 1.0363x over previous
//
#include <hip/hip_runtime.h>
#include <hip/hip_bf16.h>

#define BB 8
#define FF 64
#define NPTS 100000
#define RES 32
#define R3 (RES*RES*RES)
#define EPSV 1e-6f
#define SEGS (BB*R3)            // 262144 voxel segments (2^18)
#define NPTS_TOT (BB*NPTS)      // 800000 points

static constexpr size_t GRID_ELEMS = (size_t)BB * FF * R3;   // 16,777,216

// ---------------- Kernel A: per-batch coordinate sums ----------------
#define NB_STAT 64
__global__ void k_sum_coords(const float* __restrict__ coords, float* __restrict__ sums) {
    int b = blockIdx.x / NB_STAT;
    int chunk = blockIdx.x % NB_STAT;
    const float* cb = coords + (size_t)b * 3 * NPTS;
    float sx = 0.f, sy = 0.f, sz = 0.f;
    for (int i = chunk * blockDim.x + threadIdx.x; i < NPTS; i += NB_STAT * blockDim.x) {
        sx += cb[i];
        sy += cb[NPTS + i];
        sz += cb[2 * NPTS + i];
    }
    for (int off = 32; off; off >>= 1) {
        sx += __shfl_down(sx, off);
        sy += __shfl_down(sy, off);
        sz += __shfl_down(sz, off);
    }
    __shared__ float lsx[4], lsy[4], lsz[4];
    int lane = threadIdx.x & 63, wid = threadIdx.x >> 6;
    if (lane == 0) { lsx[wid] = sx; lsy[wid] = sy; lsz[wid] = sz; }
    __syncthreads();
    if (threadIdx.x == 0) {
        float tx = 0.f, ty = 0.f, tz = 0.f;
        for (int w = 0; w < 4; ++w) { tx += lsx[w]; ty += lsy[w]; tz += lsz[w]; }
        atomicAdd(&sums[b * 3 + 0], tx);
        atomicAdd(&sums[b * 3 + 1], ty);
        atomicAdd(&sums[b * 3 + 2], tz);
    }
}

// ---------------- Kernel B: per-batch max radius ----------------
__global__ void k_radius(const float* __restrict__ coords, const float* __restrict__ sums,
                         int* __restrict__ rad_bits) {
    int b = blockIdx.x / NB_STAT;
    int chunk = blockIdx.x % NB_STAT;
    const float* cb = coords + (size_t)b * 3 * NPTS;
    float mx = sums[b * 3 + 0] / (float)NPTS;
    float my = sums[b * 3 + 1] / (float)NPTS;
    float mz = sums[b * 3 + 2] / (float)NPTS;
    float mval = 0.f;
    for (int i = chunk * blockDim.x + threadIdx.x; i < NPTS; i += NB_STAT * blockDim.x) {
        float x = cb[i] - mx;
        float y = cb[NPTS + i] - my;
        float z = cb[2 * NPTS + i] - mz;
        float nrm = sqrtf(x * x + y * y + z * z);
        mval = fmaxf(mval, nrm);
    }
    for (int off = 32; off; off >>= 1) mval = fmaxf(mval, __shfl_down(mval, off));
    __shared__ float lm[4];
    int lane = threadIdx.x & 63, wid = threadIdx.x >> 6;
    if (lane == 0) lm[wid] = mval;
    __syncthreads();
    if (threadIdx.x == 0) {
        float t = fmaxf(fmaxf(lm[0], lm[1]), fmaxf(lm[2], lm[3]));
        atomicMax(&rad_bits[b], __float_as_int(t));  // norms >= 0: int order == float order
    }
}

// ---------------- Kernel C: per-point voxelize + norm_coords + counts ----------------
__global__ void k_voxelize(const float* __restrict__ coords, const float* __restrict__ sums,
                           const int* __restrict__ rad_bits, float* __restrict__ norm_out,
                           int* __restrict__ voxidx, int* __restrict__ counts) {
    int tid = blockIdx.x * blockDim.x + threadIdx.x;
    if (tid >= NPTS_TOT) return;
    int b = tid / NPTS, n = tid % NPTS;
    const float* cb = coords + (size_t)b * 3 * NPTS;
    float mx = sums[b * 3 + 0] / (float)NPTS;
    float my = sums[b * 3 + 1] / (float)NPTS;
    float mz = sums[b * 3 + 2] / (float)NPTS;
    float r = __int_as_float(rad_bits[b]);
    float d = 2.0f * r + EPSV;
    float x = (cb[n] - mx) / d + 0.5f;
    float y = (cb[NPTS + n] - my) / d + 0.5f;
    float z = (cb[2 * NPTS + n] - mz) / d + 0.5f;
    float nx = fminf(fmaxf(x * (float)RES, 0.0f), (float)(RES - 1));
    float ny = fminf(fmaxf(y * (float)RES, 0.0f), (float)(RES - 1));
    float nz = fminf(fmaxf(z * (float)RES, 0.0f), (float)(RES - 1));
    float* nb_ = norm_out + (size_t)b * 3 * NPTS;
    nb_[n] = nx;
    nb_[NPTS + n] = ny;
    nb_[2 * NPTS + n] = nz;
    int vx = (int)rintf(nx), vy = (int)rintf(ny), vz = (int)rintf(nz);
    int idx = (vx * RES + vy) * RES + vz;
    voxidx[tid] = idx;
    atomicAdd(&counts[b * R3 + idx], 1);
}

// ---------------- Scan: exclusive prefix sum over SEGS counts ----------------
__global__ void k_scan1(const int* __restrict__ counts, int* __restrict__ offsets,
                        int* __restrict__ blocksums) {
    int tid = threadIdx.x, bid = blockIdx.x;
    int base = bid * 1024 + tid * 4;
    int c0 = counts[base], c1 = counts[base + 1], c2 = counts[base + 2], c3 = counts[base + 3];
    int tot = c0 + c1 + c2 + c3;
    int lane = tid & 63, wid = tid >> 6;
    int v = tot;
    for (int off = 1; off < 64; off <<= 1) {
        int u = __shfl_up(v, off);
        if (lane >= off) v += u;
    }
    __shared__ int wtot[4];
    if (lane == 63) wtot[wid] = v;
    __syncthreads();
    int wof = 0;
    for (int w = 0; w < wid; ++w) wof += wtot[w];
    int ex = wof + v - tot;
    offsets[base] = ex;
    offsets[base + 1] = ex + c0;
    offsets[base + 2] = ex + c0 + c1;
    offsets[base + 3] = ex + c0 + c1 + c2;
    if (tid == 0) blocksums[bid] = wtot[0] + wtot[1] + wtot[2] + wtot[3];
}

__global__ void k_scan2(const int* __restrict__ blocksums, int* __restrict__ blockoff) {
    int tid = threadIdx.x;
    int c = blocksums[tid];
    int lane = tid & 63, wid = tid >> 6;
    int v = c;
    for (int off = 1; off < 64; off <<= 1) {
        int u = __shfl_up(v, off);
        if (lane >= off) v += u;
    }
    __shared__ int wtot[4];
    if (lane == 63) wtot[wid] = v;
    __syncthreads();
    int wof = 0;
    for (int w = 0; w < wid; ++w) wof += wtot[w];
    blockoff[tid] = wof + v - c;
}

// ---------------- Kernel D: LDS-tiled transpose + scatter into sorted bf16 rows ----------
__global__ void k_transpose_scatter(const float* __restrict__ features,
                                    const int* __restrict__ voxidx,
                                    const int* __restrict__ offsets,
                                    const int* __restrict__ blockoff,
                                    int* __restrict__ cursors,
                                    __hip_bfloat16* __restrict__ featS) {
    __shared__ float tileF[64][65];
    __shared__ int dst[64];
    int b = blockIdx.y;
    int n0 = blockIdx.x * 64;
    int tid = threadIdx.x, lane = tid & 63, wid = tid >> 6;

    for (int f = wid; f < 64; f += 4) {
        int n = n0 + lane;
        tileF[f][lane] = (n < NPTS) ? features[((size_t)b * FF + f) * NPTS + n] : 0.f;
    }
    if (tid < 64) {
        int n = n0 + tid;
        if (n < NPTS) {
            int v = voxidx[(size_t)b * NPTS + n];
            int bv = b * R3 + v;
            int r = atomicAdd(&cursors[bv], 1);
            dst[tid] = offsets[bv] + blockoff[bv >> 10] + r;
        } else {
            dst[tid] = -1;
        }
    }
    __syncthreads();
    for (int p = wid; p < 64; p += 4) {
        int d = dst[p];
        if (d >= 0) featS[(size_t)d * 64 + lane] = __float2bfloat16(tileF[lane][p]);
    }
}

// ---------------- Kernel E1: load-balanced per-wave gather + average ----------------
// One wave per voxel; waves grid-stride through a hashed (bijective) permutation of
// voxel ids so each wave gets a statistically even mix of heavy/empty voxels.
#define GATHER_BLOCKS 2048
#define GATHER_WAVES (GATHER_BLOCKS * 4)
__global__ void k_gather_avg(const ushort* __restrict__ featS,
                             const int* __restrict__ offsets,
                             const int* __restrict__ blockoff,
                             const int* __restrict__ counts,
                             float* __restrict__ avgbuf) {
    int wglob = blockIdx.x * 4 + (threadIdx.x >> 6);
    int lane = threadIdx.x & 63;
    for (int k = 0; k < SEGS / GATHER_WAVES; ++k) {
        unsigned lin = (unsigned)(k * GATHER_WAVES + wglob);
        int bv = (int)((lin * 2654435761u) & (SEGS - 1));   // odd mult mod 2^18: bijection
        int off = offsets[bv] + blockoff[bv >> 10];
        int cnt = counts[bv];
        const ushort* p = featS + (size_t)off * 64 + lane;
        float a0 = 0.f, a1 = 0.f, a2 = 0.f, a3 = 0.f, a4 = 0.f, a5 = 0.f, a6 = 0.f, a7 = 0.f;
        int i = 0;
        for (; i + 8 <= cnt; i += 8) {
            a0 += __uint_as_float((unsigned)p[(size_t)(i + 0) * 64] << 16);
            a1 += __uint_as_float((unsigned)p[(size_t)(i + 1) * 64] << 16);
            a2 += __uint_as_float((unsigned)p[(size_t)(i + 2) * 64] << 16);
            a3 += __uint_as_float((unsigned)p[(size_t)(i + 3) * 64] << 16);
            a4 += __uint_as_float((unsigned)p[(size_t)(i + 4) * 64] << 16);
            a5 += __uint_as_float((unsigned)p[(size_t)(i + 5) * 64] << 16);
            a6 += __uint_as_float((unsigned)p[(size_t)(i + 6) * 64] << 16);
            a7 += __uint_as_float((unsigned)p[(size_t)(i + 7) * 64] << 16);
        }
        for (; i < cnt; ++i) a0 += __uint_as_float((unsigned)p[(size_t)i * 64] << 16);
        float acc = ((a0 + a1) + (a2 + a3)) + ((a4 + a5) + (a6 + a7));
        avgbuf[(size_t)bv * 64 + lane] = (cnt > 0) ? acc / (float)cnt : 0.f;
    }
}

// ---------------- Kernel E2: avgbuf [BV][F] -> grid [B][F][V] (LDS transpose) ---------
__global__ void k_avg2grid(const float* __restrict__ avgbuf, float* __restrict__ grid) {
    __shared__ float tile[64][65];
    int bv0 = blockIdx.x * 64;
    int lane = threadIdx.x & 63, wid = threadIdx.x >> 6;
    for (int p = wid; p < 64; p += 4) tile[p][lane] = avgbuf[(size_t)(bv0 + p) * 64 + lane];
    __syncthreads();
    int b = bv0 >> 15;          // /R3
    int v0 = bv0 & (R3 - 1);
    for (int f = wid; f < 64; f += 4) {
        grid[((size_t)b * FF + f) * R3 + v0 + lane] = tile[lane][f];
    }
}

// ---------------- Fallback path (atomic scatter), used if ws too small ----------------
__global__ void k_scatter(const float* __restrict__ features, const int* __restrict__ voxidx,
                          float* __restrict__ grid) {
    size_t tid = (size_t)blockIdx.x * blockDim.x + threadIdx.x;
    if (tid >= (size_t)BB * FF * NPTS) return;
    int n = (int)(tid % NPTS);
    int bf = (int)(tid / NPTS);
    int b = bf >> 6;
    int idx = voxidx[(size_t)b * NPTS + n];
    atomicAdd(&grid[(size_t)bf * R3 + idx], features[tid]);
}

__global__ void k_normalize(float* __restrict__ grid, const int* __restrict__ counts) {
    size_t tid = (size_t)blockIdx.x * blockDim.x + threadIdx.x;
    if (tid >= GRID_ELEMS) return;
    int v = (int)(tid % R3);
    int bf = (int)(tid / R3);
    int b = bf >> 6;
    float c = (float)counts[b * R3 + v];
    grid[tid] = grid[tid] / fmaxf(c, 1.0f);
}

extern "C" void kernel_launch(void* const* d_in, const int* in_sizes, int n_in,
                              void* d_out, int out_size, void* d_ws, size_t ws_size,
                              hipStream_t stream) {
    const float* features = (const float*)d_in[0];
    const float* coords = (const float*)d_in[1];
    float* out = (float*)d_out;
    float* grid = out;                      // [B,F,R,R,R]
    float* norm_out = out + GRID_ELEMS;     // [B,3,N]

    char* ws = (char*)d_ws;
    size_t off_sums   = 0;                            // 24 floats
    size_t off_rad    = 128;                          // 8 ints
    size_t off_counts = 256;                          // SEGS ints (1 MB)
    size_t off_offs   = off_counts + (size_t)SEGS * 4;
    size_t off_curs   = off_offs + (size_t)SEGS * 4;
    size_t off_bsums  = off_curs + (size_t)SEGS * 4;
    size_t off_boff   = off_bsums + 256 * 4;
    size_t off_vox    = off_boff + 256 * 4;           // NPTS_TOT ints (3.2 MB)
    size_t off_featS  = (off_vox + (size_t)NPTS_TOT * 4 + 255) & ~(size_t)255;
    size_t off_avg    = (off_featS + (size_t)NPTS_TOT * FF * 2 + 255) & ~(size_t)255;
    size_t needed     = off_avg + (size_t)SEGS * FF * 4;  // ~176 MB

    float* sums    = (float*)(ws + off_sums);
    int* rad_bits  = (int*)(ws + off_rad);
    int* counts    = (int*)(ws + off_counts);
    int* offsets   = (int*)(ws + off_offs);
    int* cursors   = (int*)(ws + off_curs);
    int* blocksums = (int*)(ws + off_bsums);
    int* blockoff  = (int*)(ws + off_boff);
    int* voxidx    = (int*)(ws + off_vox);
    __hip_bfloat16* featS = (__hip_bfloat16*)(ws + off_featS);
    float* avgbuf  = (float*)(ws + off_avg);

    bool fast = (ws_size >= needed);

    if (fast) {
        hipMemsetAsync(ws, 0, off_bsums, stream);  // sums/rad/counts/offsets(junk ok)/cursors
    } else {
        hipMemsetAsync(ws, 0, off_offs, stream);   // sums/rad/counts
        hipMemsetAsync(grid, 0, GRID_ELEMS * sizeof(float), stream);
    }

    k_sum_coords<<<BB * NB_STAT, 256, 0, stream>>>(coords, sums);
    k_radius<<<BB * NB_STAT, 256, 0, stream>>>(coords, sums, rad_bits);

    int pts_blocks = (NPTS_TOT + 255) / 256;
    k_voxelize<<<pts_blocks, 256, 0, stream>>>(coords, sums, rad_bits, norm_out, voxidx, counts);

    if (fast) {
        k_scan1<<<256, 256, 0, stream>>>(counts, offsets, blocksums);
        k_scan2<<<1, 256, 0, stream>>>(blocksums, blockoff);
        dim3 tgrid((NPTS + 63) / 64, BB);
        k_transpose_scatter<<<tgrid, 256, 0, stream>>>(features, voxidx, offsets, blockoff,
                                                       cursors, featS);
        k_gather_avg<<<GATHER_BLOCKS, 256, 0, stream>>>((const ushort*)featS, offsets, blockoff,
                                                        counts, avgbuf);
        k_avg2grid<<<SEGS / 64, 256, 0, stream>>>(avgbuf, grid);
    } else {
        size_t scatter_threads = (size_t)BB * FF * NPTS;
        int scatter_blocks = (int)((scatter_threads + 255) / 256);
        k_scatter<<<scatter_blocks, 256, 0, stream>>>(features, voxidx, grid);
        int norm_blocks = (int)((GRID_ELEMS + 255) / 256);
        k_normalize<<<norm_blocks, 256, 0, stream>>>(grid, counts);
    }
}

// Round 4
// 289.064 us; speedup vs baseline: 8.7453x; 1.3273x over previous
//
#include <hip/hip_runtime.h>
#include <hip/hip_bf16.h>

#define BB 8
#define FF 64
#define NPTS 100000
#define RES 32
#define R3 (RES*RES*RES)
#define EPSV 1e-6f
#define SEGS (BB*R3)            // 262144 voxel segments (2^18)
#define NPTS_TOT (BB*NPTS)      // 800000 points (= rows in featS)
#define NWIN (NPTS_TOT/64)      // 12500 gather windows (exact)

static constexpr size_t GRID_ELEMS = (size_t)BB * FF * R3;   // 16,777,216

__device__ __forceinline__ float bf16f(ushort u) {
    return __uint_as_float((unsigned)u << 16);
}

// ---------------- Kernel A: per-batch coordinate sums ----------------
#define NB_STAT 64
__global__ void k_sum_coords(const float* __restrict__ coords, float* __restrict__ sums) {
    int b = blockIdx.x / NB_STAT;
    int chunk = blockIdx.x % NB_STAT;
    const float* cb = coords + (size_t)b * 3 * NPTS;
    float sx = 0.f, sy = 0.f, sz = 0.f;
    for (int i = chunk * blockDim.x + threadIdx.x; i < NPTS; i += NB_STAT * blockDim.x) {
        sx += cb[i];
        sy += cb[NPTS + i];
        sz += cb[2 * NPTS + i];
    }
    for (int off = 32; off; off >>= 1) {
        sx += __shfl_down(sx, off);
        sy += __shfl_down(sy, off);
        sz += __shfl_down(sz, off);
    }
    __shared__ float lsx[4], lsy[4], lsz[4];
    int lane = threadIdx.x & 63, wid = threadIdx.x >> 6;
    if (lane == 0) { lsx[wid] = sx; lsy[wid] = sy; lsz[wid] = sz; }
    __syncthreads();
    if (threadIdx.x == 0) {
        float tx = 0.f, ty = 0.f, tz = 0.f;
        for (int w = 0; w < 4; ++w) { tx += lsx[w]; ty += lsy[w]; tz += lsz[w]; }
        atomicAdd(&sums[b * 3 + 0], tx);
        atomicAdd(&sums[b * 3 + 1], ty);
        atomicAdd(&sums[b * 3 + 2], tz);
    }
}

// ---------------- Kernel B: per-batch max radius ----------------
__global__ void k_radius(const float* __restrict__ coords, const float* __restrict__ sums,
                         int* __restrict__ rad_bits) {
    int b = blockIdx.x / NB_STAT;
    int chunk = blockIdx.x % NB_STAT;
    const float* cb = coords + (size_t)b * 3 * NPTS;
    float mx = sums[b * 3 + 0] / (float)NPTS;
    float my = sums[b * 3 + 1] / (float)NPTS;
    float mz = sums[b * 3 + 2] / (float)NPTS;
    float mval = 0.f;
    for (int i = chunk * blockDim.x + threadIdx.x; i < NPTS; i += NB_STAT * blockDim.x) {
        float x = cb[i] - mx;
        float y = cb[NPTS + i] - my;
        float z = cb[2 * NPTS + i] - mz;
        float nrm = sqrtf(x * x + y * y + z * z);
        mval = fmaxf(mval, nrm);
    }
    for (int off = 32; off; off >>= 1) mval = fmaxf(mval, __shfl_down(mval, off));
    __shared__ float lm[4];
    int lane = threadIdx.x & 63, wid = threadIdx.x >> 6;
    if (lane == 0) lm[wid] = mval;
    __syncthreads();
    if (threadIdx.x == 0) {
        float t = fmaxf(fmaxf(lm[0], lm[1]), fmaxf(lm[2], lm[3]));
        atomicMax(&rad_bits[b], __float_as_int(t));  // norms >= 0: int order == float order
    }
}

// ---------------- Kernel C: per-point voxelize + norm_coords + counts ----------------
__global__ void k_voxelize(const float* __restrict__ coords, const float* __restrict__ sums,
                           const int* __restrict__ rad_bits, float* __restrict__ norm_out,
                           int* __restrict__ voxidx, int* __restrict__ counts) {
    int tid = blockIdx.x * blockDim.x + threadIdx.x;
    if (tid >= NPTS_TOT) return;
    int b = tid / NPTS, n = tid % NPTS;
    const float* cb = coords + (size_t)b * 3 * NPTS;
    float mx = sums[b * 3 + 0] / (float)NPTS;
    float my = sums[b * 3 + 1] / (float)NPTS;
    float mz = sums[b * 3 + 2] / (float)NPTS;
    float r = __int_as_float(rad_bits[b]);
    float d = 2.0f * r + EPSV;
    float x = (cb[n] - mx) / d + 0.5f;
    float y = (cb[NPTS + n] - my) / d + 0.5f;
    float z = (cb[2 * NPTS + n] - mz) / d + 0.5f;
    float nx = fminf(fmaxf(x * (float)RES, 0.0f), (float)(RES - 1));
    float ny = fminf(fmaxf(y * (float)RES, 0.0f), (float)(RES - 1));
    float nz = fminf(fmaxf(z * (float)RES, 0.0f), (float)(RES - 1));
    float* nb_ = norm_out + (size_t)b * 3 * NPTS;
    nb_[n] = nx;
    nb_[NPTS + n] = ny;
    nb_[2 * NPTS + n] = nz;
    int vx = (int)rintf(nx), vy = (int)rintf(ny), vz = (int)rintf(nz);
    int idx = (vx * RES + vy) * RES + vz;
    voxidx[tid] = idx;
    atomicAdd(&counts[b * R3 + idx], 1);
}

// ---------------- Scan: exclusive prefix sum over SEGS counts ----------------
__global__ void k_scan1(const int* __restrict__ counts, int* __restrict__ offsets,
                        int* __restrict__ blocksums) {
    int tid = threadIdx.x, bid = blockIdx.x;
    int base = bid * 1024 + tid * 4;
    int c0 = counts[base], c1 = counts[base + 1], c2 = counts[base + 2], c3 = counts[base + 3];
    int tot = c0 + c1 + c2 + c3;
    int lane = tid & 63, wid = tid >> 6;
    int v = tot;
    for (int off = 1; off < 64; off <<= 1) {
        int u = __shfl_up(v, off);
        if (lane >= off) v += u;
    }
    __shared__ int wtot[4];
    if (lane == 63) wtot[wid] = v;
    __syncthreads();
    int wof = 0;
    for (int w = 0; w < wid; ++w) wof += wtot[w];
    int ex = wof + v - tot;
    offsets[base] = ex;
    offsets[base + 1] = ex + c0;
    offsets[base + 2] = ex + c0 + c1;
    offsets[base + 3] = ex + c0 + c1 + c2;
    if (tid == 0) blocksums[bid] = wtot[0] + wtot[1] + wtot[2] + wtot[3];
}

__global__ void k_scan2(const int* __restrict__ blocksums, int* __restrict__ blockoff) {
    int tid = threadIdx.x;
    int c = blocksums[tid];
    int lane = tid & 63, wid = tid >> 6;
    int v = c;
    for (int off = 1; off < 64; off <<= 1) {
        int u = __shfl_up(v, off);
        if (lane >= off) v += u;
    }
    __shared__ int wtot[4];
    if (lane == 63) wtot[wid] = v;
    __syncthreads();
    int wof = 0;
    for (int w = 0; w < wid; ++w) wof += wtot[w];
    blockoff[tid] = wof + v - c;
}

// ---------------- Kernel C2: fill row->voxel map (sequential runs) ----------------
__global__ void k_fillvox(const int* __restrict__ offsets, const int* __restrict__ blockoff,
                          const int* __restrict__ counts, int* __restrict__ rowvox) {
    int bv = blockIdx.x * 256 + threadIdx.x;
    if (bv >= SEGS) return;
    int off = offsets[bv] + blockoff[bv >> 10];
    int cnt = counts[bv];
    for (int i = 0; i < cnt; ++i) rowvox[off + i] = bv;
}

// ---------------- Kernel D: LDS-tiled transpose + scatter into sorted bf16 rows ----------
__global__ void k_transpose_scatter(const float* __restrict__ features,
                                    const int* __restrict__ voxidx,
                                    const int* __restrict__ offsets,
                                    const int* __restrict__ blockoff,
                                    int* __restrict__ cursors,
                                    __hip_bfloat16* __restrict__ featS) {
    __shared__ float tileF[64][65];
    __shared__ int dst[64];
    int b = blockIdx.y;
    int n0 = blockIdx.x * 64;
    int tid = threadIdx.x, lane = tid & 63, wid = tid >> 6;

    for (int f = wid; f < 64; f += 4) {
        int n = n0 + lane;
        tileF[f][lane] = (n < NPTS) ? features[((size_t)b * FF + f) * NPTS + n] : 0.f;
    }
    if (tid < 64) {
        int n = n0 + tid;
        if (n < NPTS) {
            int v = voxidx[(size_t)b * NPTS + n];
            int bv = b * R3 + v;
            int r = atomicAdd(&cursors[bv], 1);
            dst[tid] = offsets[bv] + blockoff[bv >> 10] + r;
        } else {
            dst[tid] = -1;
        }
    }
    __syncthreads();
    for (int p = wid; p < 64; p += 4) {
        int d = dst[p];
        if (d >= 0) featS[(size_t)d * 64 + lane] = __float2bfloat16(tileF[lane][p]);
    }
}

// ---------------- Kernel E1: linear segmented gather + average ----------------
// One wave per 64 consecutive sorted rows (8KB contiguous). Stage window into LDS,
// detect segment starts from rowvox, sum each segment that STARTS here, write avg.
__global__ void k_gather_lin(const ushort* __restrict__ featS,
                             const int* __restrict__ rowvox,
                             const int* __restrict__ counts,
                             float* __restrict__ avgbuf) {
    __shared__ ushort tile[4][4096];   // 8KB per wave
    int wid = threadIdx.x >> 6, lane = threadIdx.x & 63;
    int w = blockIdx.x * 4 + wid;      // window id [0, NWIN)
    int r0 = w * 64;

    // stage rows r0..r0+63 (8KB linear) into LDS: 8 independent 16B loads
    const uint4* gsrc = (const uint4*)(featS + (size_t)r0 * 64);
    uint4* ldst = (uint4*)tile[wid];
    uint4 t[8];
#pragma unroll
    for (int j = 0; j < 8; ++j) t[j] = gsrc[j * 64 + lane];
#pragma unroll
    for (int j = 0; j < 8; ++j) ldst[j * 64 + lane] = t[j];

    int myrow = r0 + lane;
    int myv = rowvox[myrow];
    int prevv = __shfl_up(myv, 1);
    int pv0 = (r0 > 0) ? rowvox[r0 - 1] : -1;
    if (lane == 0) prevv = pv0;
    unsigned long long flags = __ballot(myv != prevv);

    while (flags) {
        int s = (int)__ffsll(flags) - 1;
        flags &= flags - 1;
        int bv = __shfl(myv, s);
        int cnt = flags ? ((int)__ffsll(flags) - 1 - s) : counts[bv];
        int inwin = min(cnt, 64 - s);
        float acc = 0.f;
        for (int i = 0; i < inwin; ++i) acc += bf16f(tile[wid][(s + i) * 64 + lane]);
        if (cnt > inwin) {  // overhang into following windows (last segment only)
            const ushort* p = featS + (size_t)(r0 + 64) * 64 + lane;
            int rem = cnt - inwin;
            float b0 = 0.f, b1 = 0.f, b2 = 0.f, b3 = 0.f;
            int i = 0;
            for (; i + 4 <= rem; i += 4) {
                b0 += bf16f(p[(size_t)(i + 0) * 64]);
                b1 += bf16f(p[(size_t)(i + 1) * 64]);
                b2 += bf16f(p[(size_t)(i + 2) * 64]);
                b3 += bf16f(p[(size_t)(i + 3) * 64]);
            }
            for (; i < rem; ++i) b0 += bf16f(p[(size_t)i * 64]);
            acc += (b0 + b1) + (b2 + b3);
        }
        avgbuf[(size_t)bv * 64 + lane] = acc / (float)cnt;
    }
}

// ---------------- Kernel E2: avgbuf [BV][F] -> grid [B][F][V] (LDS transpose) ---------
__global__ void k_avg2grid(const float* __restrict__ avgbuf, const int* __restrict__ counts,
                           float* __restrict__ grid) {
    __shared__ float tile[64][65];
    int bv0 = blockIdx.x * 64;
    int lane = threadIdx.x & 63, wid = threadIdx.x >> 6;
    for (int p = wid; p < 64; p += 4) {
        int cnt = counts[bv0 + p];
        tile[p][lane] = (cnt > 0) ? avgbuf[(size_t)(bv0 + p) * 64 + lane] : 0.f;
    }
    __syncthreads();
    int b = bv0 >> 15;          // /R3
    int v0 = bv0 & (R3 - 1);
    for (int f = wid; f < 64; f += 4) {
        grid[((size_t)b * FF + f) * R3 + v0 + lane] = tile[lane][f];
    }
}

// ---------------- Fallback path (atomic scatter), used if ws too small ----------------
__global__ void k_scatter(const float* __restrict__ features, const int* __restrict__ voxidx,
                          float* __restrict__ grid) {
    size_t tid = (size_t)blockIdx.x * blockDim.x + threadIdx.x;
    if (tid >= (size_t)BB * FF * NPTS) return;
    int n = (int)(tid % NPTS);
    int bf = (int)(tid / NPTS);
    int b = bf >> 6;
    int idx = voxidx[(size_t)b * NPTS + n];
    atomicAdd(&grid[(size_t)bf * R3 + idx], features[tid]);
}

__global__ void k_normalize(float* __restrict__ grid, const int* __restrict__ counts) {
    size_t tid = (size_t)blockIdx.x * blockDim.x + threadIdx.x;
    if (tid >= GRID_ELEMS) return;
    int v = (int)(tid % R3);
    int bf = (int)(tid / R3);
    int b = bf >> 6;
    float c = (float)counts[b * R3 + v];
    grid[tid] = grid[tid] / fmaxf(c, 1.0f);
}

extern "C" void kernel_launch(void* const* d_in, const int* in_sizes, int n_in,
                              void* d_out, int out_size, void* d_ws, size_t ws_size,
                              hipStream_t stream) {
    const float* features = (const float*)d_in[0];
    const float* coords = (const float*)d_in[1];
    float* out = (float*)d_out;
    float* grid = out;                      // [B,F,R,R,R]
    float* norm_out = out + GRID_ELEMS;     // [B,3,N]

    char* ws = (char*)d_ws;
    size_t off_sums   = 0;                            // 24 floats
    size_t off_rad    = 128;                          // 8 ints
    size_t off_counts = 256;                          // SEGS ints (1 MB)
    size_t off_offs   = off_counts + (size_t)SEGS * 4;
    size_t off_curs   = off_offs + (size_t)SEGS * 4;
    size_t off_bsums  = off_curs + (size_t)SEGS * 4;
    size_t off_boff   = off_bsums + 256 * 4;
    size_t off_vox    = off_boff + 256 * 4;           // NPTS_TOT ints (3.2 MB)
    size_t off_rowv   = off_vox + (size_t)NPTS_TOT * 4;  // NPTS_TOT ints (3.2 MB)
    size_t off_featS  = (off_rowv + (size_t)NPTS_TOT * 4 + 255) & ~(size_t)255;
    size_t off_avg    = (off_featS + (size_t)NPTS_TOT * FF * 2 + 255) & ~(size_t)255;
    size_t needed     = off_avg + (size_t)SEGS * FF * 4;  // ~180 MB

    float* sums    = (float*)(ws + off_sums);
    int* rad_bits  = (int*)(ws + off_rad);
    int* counts    = (int*)(ws + off_counts);
    int* offsets   = (int*)(ws + off_offs);
    int* cursors   = (int*)(ws + off_curs);
    int* blocksums = (int*)(ws + off_bsums);
    int* blockoff  = (int*)(ws + off_boff);
    int* voxidx    = (int*)(ws + off_vox);
    int* rowvox    = (int*)(ws + off_rowv);
    __hip_bfloat16* featS = (__hip_bfloat16*)(ws + off_featS);
    float* avgbuf  = (float*)(ws + off_avg);

    bool fast = (ws_size >= needed);

    if (fast) {
        hipMemsetAsync(ws, 0, off_bsums, stream);  // sums/rad/counts/offsets(junk ok)/cursors
    } else {
        hipMemsetAsync(ws, 0, off_offs, stream);   // sums/rad/counts
        hipMemsetAsync(grid, 0, GRID_ELEMS * sizeof(float), stream);
    }

    k_sum_coords<<<BB * NB_STAT, 256, 0, stream>>>(coords, sums);
    k_radius<<<BB * NB_STAT, 256, 0, stream>>>(coords, sums, rad_bits);

    int pts_blocks = (NPTS_TOT + 255) / 256;
    k_voxelize<<<pts_blocks, 256, 0, stream>>>(coords, sums, rad_bits, norm_out, voxidx, counts);

    if (fast) {
        k_scan1<<<256, 256, 0, stream>>>(counts, offsets, blocksums);
        k_scan2<<<1, 256, 0, stream>>>(blocksums, blockoff);
        k_fillvox<<<(SEGS + 255) / 256, 256, 0, stream>>>(offsets, blockoff, counts, rowvox);
        dim3 tgrid((NPTS + 63) / 64, BB);
        k_transpose_scatter<<<tgrid, 256, 0, stream>>>(features, voxidx, offsets, blockoff,
                                                       cursors, featS);
        k_gather_lin<<<NWIN / 4, 256, 0, stream>>>((const ushort*)featS, rowvox, counts, avgbuf);
        k_avg2grid<<<SEGS / 64, 256, 0, stream>>>(avgbuf, counts, grid);
    } else {
        size_t scatter_threads = (size_t)BB * FF * NPTS;
        int scatter_blocks = (int)((scatter_threads + 255) / 256);
        k_scatter<<<scatter_blocks, 256, 0, stream>>>(features, voxidx, grid);
        int norm_blocks = (int)((GRID_ELEMS + 255) / 256);
        k_normalize<<<norm_blocks, 256, 0, stream>>>(grid, counts);
    }
}